// Round 9
// baseline (1565.136 us; speedup 1.0000x reference)
//
#include <hip/hip_runtime.h>
#include <float.h>
#include <math.h>

#define B_SZ   2048
#define D_DIM  256
#define P_DIM  4
#define N_TOT  4096        // 2*B
#define EPS_F  1e-8f
#define RPP    16          // rows per panel
#define NBK    1024        // buckets per row histogram
#define BSCALE 256.0f      // bucket width 1/256; tie-approx err ~1.3e-2 << 0.146
#define CSPLIT 4           // column chunks per panel (occupancy)

typedef short  s16x8 __attribute__((ext_vector_type(8)));
typedef float  f32x4 __attribute__((ext_vector_type(4)));

__device__ __forceinline__ unsigned short f2bf(float x) {
    unsigned int b = __float_as_uint(x);
    b += 0x7FFFu + ((b >> 16) & 1u);        // RNE
    return (unsigned short)(b >> 16);
}

// ---------------- Kernel Z: zero the global histogram (replaces hipMemsetAsync) ----------------
__global__ __launch_bounds__(256) void zero_kernel(float4* __restrict__ p, int n4)
{
    int stride = gridDim.x * 256;
    float4 z = {0.f, 0.f, 0.f, 0.f};
    for (int i = blockIdx.x * 256 + threadIdx.x; i < n4; i += stride)
        p[i] = z;
}

// ---------------- Kernel A: row-normalize features -> bf16 ----------------
__global__ __launch_bounds__(64) void normalize_kernel(
    const float* __restrict__ z_i, const float* __restrict__ z_j,
    unsigned short* __restrict__ fb)
{
    int row  = blockIdx.x;
    int lane = threadIdx.x;
    const float* src = (row < B_SZ) ? (z_i + (size_t)row * D_DIM)
                                    : (z_j + (size_t)(row - B_SZ) * D_DIM);
    float4 v = ((const float4*)src)[lane];
    float ss = v.x*v.x + v.y*v.y + v.z*v.z + v.w*v.w;
    #pragma unroll
    for (int off = 32; off > 0; off >>= 1)
        ss += __shfl_down(ss, off, 64);
    ss = __shfl(ss, 0, 64);
    float inv = 1.0f / sqrtf(ss);
    ushort4 o;
    o.x = f2bf(v.x * inv); o.y = f2bf(v.y * inv);
    o.z = f2bf(v.z * inv); o.w = f2bf(v.w * inv);
    ((ushort4*)(fb + (size_t)row * D_DIM))[lane] = o;
}

// ---------------- Kernel B: panel logits + GLOBAL-atomic histogram (no LDS) ----------------
// R0-R7 invariant wall diagnosis: every variant (~100-180us) funneled ~N^2 data-
// dependent f32 atomicAdds through the per-CU LDS pipe while all issue counters sat
// idle (R7: VALU 7.7%, MFMA 1.8%, HBM 0.6%, conflicts 0 -> ~165us of untagged stall).
// This version has ZERO LDS atomics: exp/cnt are binned via fire-and-forget DEVICE
// atomics into a 32MB global histogram (drained by TCC across the L2 channels; waves
// never wait on the RMW). No LDS buffers at all -> grid 1024 (4 col-chunks/panel) x 8
// waves gives deep TLP. This doubles as the decisive ablation: if this still runs
// >~120us, the LDS-atomic theory is falsified and the b-load/MFMA chain is the wall.
__global__ __launch_bounds__(512) void panel_pass1(
    const unsigned short* __restrict__ fb,
    const float* __restrict__ physics_i, const float* __restrict__ physics_j,
    float* __restrict__ ghist, float* __restrict__ partial)
{
    __shared__ float scr[8];

    int tid = threadIdx.x;
    int L   = tid & 63;
    int w   = tid >> 6;                      // 0..7
    int pnl = blockIdx.x >> 2;               // panel: consecutive ids share a-rows (L2)
    int cc  = blockIdx.x & (CSPLIT - 1);     // column chunk
    int i0  = pnl * RPP;

    // A-fragments: lane holds panel row i0+(L&15), k = kc*32 + (L>>4)*8 .. +8
    // (fragment scheme correctness-proven in R6/R7 passing kernels)
    s16x8 a[8];
    #pragma unroll
    for (int kc = 0; kc < 8; ++kc)
        a[kc] = *(const s16x8*)(fb + (size_t)(i0 + (L & 15)) * D_DIM
                                + kc * 32 + (L >> 4) * 8);

    // labels for this lane's 4 output rows (C row = (L>>4)*4 + q)
    float4 Lr[4];
    #pragma unroll
    for (int q = 0; q < 4; ++q) {
        int r = i0 + (L >> 4) * 4 + q;
        const float* p = (r < B_SZ) ? physics_i + (size_t)r * P_DIM
                                    : physics_j + (size_t)(r - B_SZ) * P_DIM;
        Lr[q] = *(const float4*)p;
    }

    // ---- 8 iters x (8 waves x 16 cols) = this chunk's 1024 columns ----
    float SL = 0.f;
    for (int ct = 0; ct < 8; ++ct) {
        int jc = cc * 1024 + ct * 128 + w * 16 + (L & 15);

        const unsigned short* bp = fb + (size_t)jc * D_DIM + (L >> 4) * 8;
        s16x8 b[8];
        #pragma unroll
        for (int kc = 0; kc < 8; ++kc)
            b[kc] = *(const s16x8*)(bp + kc * 32);
        const float* pj = (jc < B_SZ) ? physics_i + (size_t)jc * P_DIM
                                      : physics_j + (size_t)(jc - B_SZ) * P_DIM;
        float4 Lj = *(const float4*)pj;

        f32x4 acc0 = {0.f, 0.f, 0.f, 0.f};  // two chains: halve MFMA dep latency
        f32x4 acc1 = {0.f, 0.f, 0.f, 0.f};
        #pragma unroll
        for (int kc = 0; kc < 4; ++kc) {
            acc0 = __builtin_amdgcn_mfma_f32_16x16x32_bf16(a[2*kc],   b[2*kc],   acc0, 0, 0, 0);
            acc1 = __builtin_amdgcn_mfma_f32_16x16x32_bf16(a[2*kc+1], b[2*kc+1], acc1, 0, 0, 0);
        }

        #pragma unroll
        for (int q = 0; q < 4; ++q) {
            int rq = (L >> 4) * 4 + q;
            float logit = (acc0[q] + acc1[q]) * 0.5f;          // /TEMP
            float d = fabsf(Lr[q].x - Lj.x) + fabsf(Lr[q].y - Lj.y)
                    + fabsf(Lr[q].z - Lj.z) + fabsf(Lr[q].w - Lj.w);
            int bk = (int)(d * BSCALE); if (bk > NBK - 1) bk = NBK - 1;
            if (jc != i0 + rq) {
                float* cell = ghist + (((size_t)(i0 + rq) << 10) + bk) * 2;
                atomicAdd(cell,     __expf(logit));            // fire-and-forget
                atomicAdd(cell + 1, 1.0f);
                SL += logit;
            }
        }
    }

    // ---- block reduce of -SL ----
    #pragma unroll
    for (int off = 32; off > 0; off >>= 1)
        SL += __shfl_down(SL, off, 64);
    if (L == 0) scr[w] = SL;
    __syncthreads();
    if (tid == 0) {
        float s = 0.f;
        #pragma unroll
        for (int w2 = 0; w2 < 8; ++w2) s += scr[w2];
        partial[blockIdx.x] = -s;
    }
}

// ---------------- Kernel C: per-row suffix-CDF + count-weighted log sum ----------------
__global__ __launch_bounds__(256) void cdf_kernel(
    const float* __restrict__ ghist, float* __restrict__ rowres)
{
    __shared__ float scr[4];
    int tid  = threadIdx.x;
    int lane = tid & 63;
    int wid  = tid >> 6;                     // 4 waves
    int row  = blockIdx.x;

    // thread owns buckets [tid*4, tid*4+4); interleaved (sum,cnt) pairs
    const float* base = ghist + ((size_t)row << 10) * 2 + tid * 8;
    float4 v0 = *(const float4*)(base);      // s0 c0 s1 c1
    float4 v1 = *(const float4*)(base + 4);  // s2 c2 s3 c3

    float fs = v0.x + v0.z + v1.x + v1.z;
    float s  = fs;
    #pragma unroll
    for (int off = 1; off < 64; off <<= 1) { // intra-wave suffix scan
        float u = __shfl_down(s, off, 64);
        if (lane + off < 64) s += u;
    }
    if (lane == 0) scr[wid] = s;             // wave totals
    __syncthreads();
    float sb = 0.f;
    #pragma unroll
    for (int w2 = wid + 1; w2 < 4; ++w2) sb += scr[w2];

    float run  = sb + s - fs;                // sum of buckets strictly above mine
    float term = 0.f;
    run += v1.z; term += v1.w * __logf(run + EPS_F);   // bucket 3
    run += v1.x; term += v1.y * __logf(run + EPS_F);   // bucket 2
    run += v0.z; term += v0.w * __logf(run + EPS_F);   // bucket 1
    run += v0.x; term += v0.y * __logf(run + EPS_F);   // bucket 0

    #pragma unroll
    for (int off = 32; off > 0; off >>= 1)
        term += __shfl_down(term, off, 64);
    __syncthreads();                         // scr reuse
    if (lane == 0) scr[wid] = term;
    __syncthreads();
    if (tid == 0)
        rowres[row] = scr[0] + scr[1] + scr[2] + scr[3];
}

// ---------------- Kernel D: final reduce (4096 row terms + 1024 -SL partials) ----------------
__global__ __launch_bounds__(256) void final_kernel(
    const float* __restrict__ rowres, const float* __restrict__ partial,
    float* __restrict__ out)
{
    __shared__ float red[4];
    int tid = threadIdx.x;
    float s = 0.f;
    for (int i = tid; i < N_TOT; i += 256) s += rowres[i];
    for (int i = tid; i < N_TOT / RPP * CSPLIT; i += 256) s += partial[i];
    #pragma unroll
    for (int off = 32; off > 0; off >>= 1)
        s += __shfl_down(s, off, 64);
    if ((tid & 63) == 0) red[tid >> 6] = s;
    __syncthreads();
    if (tid == 0) {
        double tot = (double)red[0] + red[1] + red[2] + red[3];
        out[0] = (float)(tot / ((double)N_TOT * (N_TOT - 1)));
    }
}

extern "C" void kernel_launch(void* const* d_in, const int* in_sizes, int n_in,
                              void* d_out, int out_size, void* d_ws, size_t ws_size,
                              hipStream_t stream)
{
    const float* z_i  = (const float*)d_in[0];
    const float* z_j  = (const float*)d_in[1];
    const float* ph_i = (const float*)d_in[2];
    const float* ph_j = (const float*)d_in[3];

    unsigned short* fb      = (unsigned short*)d_ws;                   // 2 MB bf16
    float*          ghist   = (float*)(fb + (size_t)N_TOT * D_DIM);    // 32 MB
    float*          rowres  = ghist + (size_t)N_TOT * NBK * 2;         // 16 KB
    float*          partial = rowres + N_TOT;                          // 4 KB

    zero_kernel<<<2048, 256, 0, stream>>>((float4*)ghist,
                                          (int)((size_t)N_TOT * NBK * 2 / 4));
    normalize_kernel<<<N_TOT, 64, 0, stream>>>(z_i, z_j, fb);
    panel_pass1<<<N_TOT / RPP * CSPLIT, 512, 0, stream>>>(fb, ph_i, ph_j, ghist, partial);
    cdf_kernel<<<N_TOT, 256, 0, stream>>>(ghist, rowres);
    final_kernel<<<1, 256, 0, stream>>>(rowres, partial, (float*)d_out);
}

// Round 10
// 217.192 us; speedup vs baseline: 7.2062x; 7.2062x over previous
//
#include <hip/hip_runtime.h>
#include <float.h>
#include <math.h>

#define B_SZ   2048
#define D_DIM  256
#define P_DIM  4
#define N_TOT  4096        // 2*B
#define EPS_F  1e-8f
#define RPP    16          // rows per panel
#define NBK    512         // buckets per row histogram
#define BSCALE 128.0f      // bucket width 1/128; tie-approx err ~2.6e-2 << 0.146

typedef short  s16x8 __attribute__((ext_vector_type(8)));
typedef float  f32x4 __attribute__((ext_vector_type(4)));

__device__ __forceinline__ unsigned short f2bf(float x) {
    unsigned int b = __float_as_uint(x);
    b += 0x7FFFu + ((b >> 16) & 1u);        // RNE
    return (unsigned short)(b >> 16);
}

// ---------------- Kernel A: row-normalize features -> bf16 ----------------
__global__ __launch_bounds__(64) void normalize_kernel(
    const float* __restrict__ z_i, const float* __restrict__ z_j,
    unsigned short* __restrict__ fb)
{
    int row  = blockIdx.x;
    int lane = threadIdx.x;
    const float* src = (row < B_SZ) ? (z_i + (size_t)row * D_DIM)
                                    : (z_j + (size_t)(row - B_SZ) * D_DIM);
    float4 v = ((const float4*)src)[lane];
    float ss = v.x*v.x + v.y*v.y + v.z*v.z + v.w*v.w;
    #pragma unroll
    for (int off = 32; off > 0; off >>= 1)
        ss += __shfl_down(ss, off, 64);
    ss = __shfl(ss, 0, 64);
    float inv = 1.0f / sqrtf(ss);
    ushort4 o;
    o.x = f2bf(v.x * inv); o.y = f2bf(v.y * inv);
    o.z = f2bf(v.z * inv); o.w = f2bf(v.w * inv);
    ((ushort4*)(fb + (size_t)row * D_DIM))[lane] = o;
}

// ---------------- Kernel B (FUSED, 2-pass, LDS hist): panel loss ----------------
// R9 falsified global atomics (1482us, 1GB writeback). Back to LDS with the three
// measured pathologies fixed:
//  1. PLAIN hist layout rq*512+bk: bank = bk&31 = FINE distance bits (uniform).
//     R6/R7's swizzle put bk>>4 (coarse, concentrated ~10 banks) in the bank bits.
//  2. 2-pass: 1 atomic/pair (16.7M total, R6-style). The 2nd GEMM is free
//     (MfmaUtil 1.8% -> ~7us of MFMA in a 180us kernel).
//  3. asm-pinned a[]/Lr[]: every prior round the allocator picked VGPR 48-60 <
//     live set and rematerialized a[] from L2 inside the loop (WRITE_SIZE small ->
//     remat not spill). volatile asm can't be re-executed -> values stay resident.
__global__ __launch_bounds__(1024, 4) void panel_kernel(
    const unsigned short* __restrict__ fb,
    const float* __restrict__ physics_i, const float* __restrict__ physics_j,
    float* __restrict__ partial)
{
    __shared__ float hist[RPP * NBK];        // 32 KB, plain layout
    __shared__ float scr[16];

    int tid = threadIdx.x;
    int L   = tid & 63;
    int w   = tid >> 6;                      // 0..15
    int i0  = blockIdx.x * RPP;

    float4 z4 = {0.f, 0.f, 0.f, 0.f};
    ((float4*)hist)[tid]        = z4;        // 2048 float4 = 8192 floats
    ((float4*)hist)[tid + 1024] = z4;

    // A-fragments: lane holds panel row i0+(L&15), k = kc*32 + (L>>4)*8 .. +8
    // (fragment scheme correctness-proven R6-R9). Stored as uint4 + pinned.
    uint4 a4[8];
    #pragma unroll
    for (int kc = 0; kc < 8; ++kc)
        a4[kc] = *(const uint4*)(fb + (size_t)(i0 + (L & 15)) * D_DIM
                                 + kc * 32 + (L >> 4) * 8);
    #pragma unroll
    for (int kc = 0; kc < 8; ++kc)
        asm volatile("" : "+v"(a4[kc].x), "+v"(a4[kc].y),
                          "+v"(a4[kc].z), "+v"(a4[kc].w));

    // labels for this lane's 4 output rows (C row = (L>>4)*4 + q), pinned
    float4 Lr[4];
    #pragma unroll
    for (int q = 0; q < 4; ++q) {
        int r = i0 + (L >> 4) * 4 + q;
        const float* p = (r < B_SZ) ? physics_i + (size_t)r * P_DIM
                                    : physics_j + (size_t)(r - B_SZ) * P_DIM;
        Lr[q] = *(const float4*)p;
    }
    #pragma unroll
    for (int q = 0; q < 4; ++q)
        asm volatile("" : "+v"(Lr[q].x), "+v"(Lr[q].y),
                          "+v"(Lr[q].z), "+v"(Lr[q].w));

    __syncthreads();                         // B0: zeros visible

    // ---- pass 1: bin exp(logit) into per-row histograms (1 LDS atomic/pair) ----
    for (int ct = 0; ct < 16; ++ct) {
        int jc = ct * 256 + w * 16 + (L & 15);   // 16 waves x 16 cols = 256 cols/iter

        const unsigned short* bp = fb + (size_t)jc * D_DIM + (L >> 4) * 8;
        s16x8 b[8];
        #pragma unroll
        for (int kc = 0; kc < 8; ++kc)
            b[kc] = *(const s16x8*)(bp + kc * 32);
        const float* pj = (jc < B_SZ) ? physics_i + (size_t)jc * P_DIM
                                      : physics_j + (size_t)(jc - B_SZ) * P_DIM;
        float4 Lj = *(const float4*)pj;

        f32x4 acc0 = {0.f, 0.f, 0.f, 0.f};
        f32x4 acc1 = {0.f, 0.f, 0.f, 0.f};
        #pragma unroll
        for (int kc = 0; kc < 4; ++kc) {
            acc0 = __builtin_amdgcn_mfma_f32_16x16x32_bf16(
                __builtin_bit_cast(s16x8, a4[2*kc]),   b[2*kc],   acc0, 0, 0, 0);
            acc1 = __builtin_amdgcn_mfma_f32_16x16x32_bf16(
                __builtin_bit_cast(s16x8, a4[2*kc+1]), b[2*kc+1], acc1, 0, 0, 0);
        }

        #pragma unroll
        for (int q = 0; q < 4; ++q) {
            int rq = (L >> 4) * 4 + q;
            float logit = (acc0[q] + acc1[q]) * 0.5f;          // /TEMP
            float d = fabsf(Lr[q].x - Lj.x) + fabsf(Lr[q].y - Lj.y)
                    + fabsf(Lr[q].z - Lj.z) + fabsf(Lr[q].w - Lj.w);
            int bk = (int)(d * BSCALE); if (bk > NBK - 1) bk = NBK - 1;
            if (jc != i0 + rq)
                atomicAdd(&hist[rq * NBK + bk], __expf(logit));
        }
    }
    __syncthreads();                         // B1: histograms complete

    // ---- in-place suffix CDF; wave w owns row w; lane owns buckets [8L, 8L+8) ----
    {
        float* hrow = hist + w * NBK + L * 8;
        float v[8];
        float fs = 0.f;
        #pragma unroll
        for (int k = 0; k < 8; ++k) { v[k] = hrow[k]; fs += v[k]; }
        float s = fs;
        #pragma unroll
        for (int off = 1; off < 64; off <<= 1) {   // inclusive suffix over lanes
            float u = __shfl_down(s, off, 64);
            if (L + off < 64) s += u;
        }
        float run = s - fs;                  // strictly-above-lane sum
        #pragma unroll
        for (int k = 7; k >= 0; --k) { run += v[k]; hrow[k] = run; }
    }
    __syncthreads();                         // B2: CDF ready

    // ---- pass 2: recompute logits, ACC += logit - log(denom) ----
    float ACC = 0.f;
    for (int ct = 0; ct < 16; ++ct) {
        int jc = ct * 256 + w * 16 + (L & 15);

        const unsigned short* bp = fb + (size_t)jc * D_DIM + (L >> 4) * 8;
        s16x8 b[8];
        #pragma unroll
        for (int kc = 0; kc < 8; ++kc)
            b[kc] = *(const s16x8*)(bp + kc * 32);
        const float* pj = (jc < B_SZ) ? physics_i + (size_t)jc * P_DIM
                                      : physics_j + (size_t)(jc - B_SZ) * P_DIM;
        float4 Lj = *(const float4*)pj;

        f32x4 acc0 = {0.f, 0.f, 0.f, 0.f};
        f32x4 acc1 = {0.f, 0.f, 0.f, 0.f};
        #pragma unroll
        for (int kc = 0; kc < 4; ++kc) {
            acc0 = __builtin_amdgcn_mfma_f32_16x16x32_bf16(
                __builtin_bit_cast(s16x8, a4[2*kc]),   b[2*kc],   acc0, 0, 0, 0);
            acc1 = __builtin_amdgcn_mfma_f32_16x16x32_bf16(
                __builtin_bit_cast(s16x8, a4[2*kc+1]), b[2*kc+1], acc1, 0, 0, 0);
        }

        #pragma unroll
        for (int q = 0; q < 4; ++q) {
            int rq = (L >> 4) * 4 + q;
            float logit = (acc0[q] + acc1[q]) * 0.5f;
            float d = fabsf(Lr[q].x - Lj.x) + fabsf(Lr[q].y - Lj.y)
                    + fabsf(Lr[q].z - Lj.z) + fabsf(Lr[q].w - Lj.w);
            int bk = (int)(d * BSCALE); if (bk > NBK - 1) bk = NBK - 1;
            if (jc != i0 + rq)
                ACC += logit - __logf(hist[rq * NBK + bk] + EPS_F);
        }
    }

    // ---- block reduce of ACC (sum of pos_log_probs) ----
    #pragma unroll
    for (int off = 32; off > 0; off >>= 1)
        ACC += __shfl_down(ACC, off, 64);
    if (L == 0) scr[w] = ACC;
    __syncthreads();                         // B3
    if (tid == 0) {
        float s = 0.f;
        #pragma unroll
        for (int w2 = 0; w2 < 16; ++w2) s += scr[w2];
        partial[blockIdx.x] = s;
    }
}

// ---------------- Kernel C: final reduce (256 panel partials) ----------------
__global__ __launch_bounds__(256) void final_kernel(
    const float* __restrict__ partial, float* __restrict__ out)
{
    __shared__ float red[4];
    int tid = threadIdx.x;
    float s = 0.f;
    for (int i = tid; i < N_TOT / RPP; i += 256) s += partial[i];
    #pragma unroll
    for (int off = 32; off > 0; off >>= 1)
        s += __shfl_down(s, off, 64);
    if ((tid & 63) == 0) red[tid >> 6] = s;
    __syncthreads();
    if (tid == 0) {
        double tot = (double)red[0] + red[1] + red[2] + red[3];
        out[0] = (float)(-tot / ((double)N_TOT * (N_TOT - 1)));   // loss = -sum/(n(n-1))
    }
}

extern "C" void kernel_launch(void* const* d_in, const int* in_sizes, int n_in,
                              void* d_out, int out_size, void* d_ws, size_t ws_size,
                              hipStream_t stream)
{
    const float* z_i  = (const float*)d_in[0];
    const float* z_j  = (const float*)d_in[1];
    const float* ph_i = (const float*)d_in[2];
    const float* ph_j = (const float*)d_in[3];

    unsigned short* fb      = (unsigned short*)d_ws;                  // 2 MB bf16
    float*          partial = (float*)(fb + (size_t)N_TOT * D_DIM);   // 1 KB

    normalize_kernel<<<N_TOT, 64, 0, stream>>>(z_i, z_j, fb);
    panel_kernel<<<N_TOT / RPP, 1024, 0, stream>>>(fb, ph_i, ph_j, partial);
    final_kernel<<<1, 256, 0, stream>>>(partial, (float*)d_out);
}

// Round 11
// 159.616 us; speedup vs baseline: 9.8056x; 1.3607x over previous
//
#include <hip/hip_runtime.h>
#include <float.h>
#include <math.h>

#define B_SZ   2048
#define D_DIM  256
#define P_DIM  4
#define N_TOT  4096        // 2*B
#define EPS_F  1e-8f
#define RPP    16          // rows per panel
#define NBK    512         // buckets per row histogram
#define BSCALE 128.0f      // bucket width 1/128; tie-approx err ~2.6e-2 << 0.146 (R10-validated)

typedef short  s16x8 __attribute__((ext_vector_type(8)));
typedef float  f32x4 __attribute__((ext_vector_type(4)));

__device__ __forceinline__ unsigned short f2bf(float x) {
    unsigned int b = __float_as_uint(x);
    b += 0x7FFFu + ((b >> 16) & 1u);        // RNE
    return (unsigned short)(b >> 16);
}

// ---------------- Kernel A: row-normalize features -> bf16 ----------------
__global__ __launch_bounds__(64) void normalize_kernel(
    const float* __restrict__ z_i, const float* __restrict__ z_j,
    unsigned short* __restrict__ fb)
{
    int row  = blockIdx.x;
    int lane = threadIdx.x;
    const float* src = (row < B_SZ) ? (z_i + (size_t)row * D_DIM)
                                    : (z_j + (size_t)(row - B_SZ) * D_DIM);
    float4 v = ((const float4*)src)[lane];
    float ss = v.x*v.x + v.y*v.y + v.z*v.z + v.w*v.w;
    #pragma unroll
    for (int off = 32; off > 0; off >>= 1)
        ss += __shfl_down(ss, off, 64);
    ss = __shfl(ss, 0, 64);
    float inv = 1.0f / sqrtf(ss);
    ushort4 o;
    o.x = f2bf(v.x * inv); o.y = f2bf(v.y * inv);
    o.z = f2bf(v.z * inv); o.w = f2bf(v.w * inv);
    ((ushort4*)(fb + (size_t)row * D_DIM))[lane] = o;
}

// ---------------- Kernel B (FUSED, SINGLE-pass, software-pipelined) ----------------
// R6/R7/R10 triangulation: neither atomic count (16.7M vs 33M) nor pass count moves
// time (160-180us, issue ~30us) -> the wall is per-ct serial L2-load -> MFMA -> bin
// chains with no lookahead (allocator never granted in-flight regs; VGPR 52-60 every
// round). Fixes here:
//  - 512-thread block (8 waves): launch_bounds(512,2) -> 256-VGPR budget, room for
//    a full double-buffer of b-fragments.
//  - EXPLICIT sw pipeline: named bufA/bufB (static indexing), prefetch ct+1 while
//    computing ct -> L2 latency hides under MFMA+VALU of the previous tile.
//  - single pass: count-histogram trick (sum_j log(denom_j) = sum_bk cnt*log(CDF));
//    counts via packed-u16 LDS atomic (row pair shares a u32 word).
__global__ __launch_bounds__(512, 2) void panel_kernel(
    const unsigned short* __restrict__ fb,
    const float* __restrict__ physics_i, const float* __restrict__ physics_j,
    float* __restrict__ partial)
{
    __shared__ float    hsum[RPP * NBK];          // 32 KB, plain layout (bank = bk&31)
    __shared__ unsigned hcnt[(RPP / 2) * NBK];    // 16 KB, u16-packed row pairs
    __shared__ float    scr[8];

    int tid = threadIdx.x;
    int L   = tid & 63;
    int w   = tid >> 6;                      // 0..7
    int i0  = blockIdx.x * RPP;

    float4 z4 = {0.f, 0.f, 0.f, 0.f};
    uint4  zu = {0u, 0u, 0u, 0u};
    #pragma unroll
    for (int t = 0; t < 4; ++t) ((float4*)hsum)[tid + t * 512] = z4;  // 2048 float4
    #pragma unroll
    for (int t = 0; t < 2; ++t) ((uint4*)hcnt)[tid + t * 512] = zu;   // 1024 uint4

    // A-fragments (proven layout R6-R10): lane holds row i0+(L&15), k-chunk kc at
    // k = kc*32 + (L>>4)*8
    uint4 a4[8];
    #pragma unroll
    for (int kc = 0; kc < 8; ++kc)
        a4[kc] = *(const uint4*)(fb + (size_t)(i0 + (L & 15)) * D_DIM
                                 + kc * 32 + (L >> 4) * 8);
    // labels for this lane's 4 output rows (C row = (L>>4)*4 + q)
    float4 Lr[4];
    #pragma unroll
    for (int q = 0; q < 4; ++q) {
        int r = i0 + (L >> 4) * 4 + q;
        const float* p = (r < B_SZ) ? physics_i + (size_t)r * P_DIM
                                    : physics_j + (size_t)(r - B_SZ) * P_DIM;
        Lr[q] = *(const float4*)p;
    }

    __syncthreads();                         // B0: zeros visible

    #define LOADB(BB, LJ, ct)                                                     \
        {                                                                         \
            int jc_ = (ct) * 128 + w * 16 + (L & 15);                             \
            const unsigned short* bp_ = fb + (size_t)jc_ * D_DIM + (L >> 4) * 8;  \
            _Pragma("unroll")                                                     \
            for (int kc = 0; kc < 8; ++kc)                                        \
                BB[kc] = *(const s16x8*)(bp_ + kc * 32);                          \
            const float* pj_ = (jc_ < B_SZ)                                       \
                ? physics_i + (size_t)jc_ * P_DIM                                 \
                : physics_j + (size_t)(jc_ - B_SZ) * P_DIM;                       \
            LJ = *(const float4*)pj_;                                             \
        }

    #define COMPUTE(BB, LJ, ct)                                                   \
        {                                                                         \
            int jc_ = (ct) * 128 + w * 16 + (L & 15);                             \
            f32x4 acc0 = {0.f, 0.f, 0.f, 0.f};                                    \
            f32x4 acc1 = {0.f, 0.f, 0.f, 0.f};                                    \
            _Pragma("unroll")                                                     \
            for (int kc = 0; kc < 4; ++kc) {                                      \
                acc0 = __builtin_amdgcn_mfma_f32_16x16x32_bf16(                   \
                    __builtin_bit_cast(s16x8, a4[2*kc]),   BB[2*kc],   acc0, 0, 0, 0); \
                acc1 = __builtin_amdgcn_mfma_f32_16x16x32_bf16(                   \
                    __builtin_bit_cast(s16x8, a4[2*kc+1]), BB[2*kc+1], acc1, 0, 0, 0); \
            }                                                                     \
            _Pragma("unroll")                                                     \
            for (int q = 0; q < 4; ++q) {                                         \
                int rq = (L >> 4) * 4 + q;                                        \
                float logit = (acc0[q] + acc1[q]) * 0.5f;  /* /TEMP */            \
                float d = fabsf(Lr[q].x - LJ.x) + fabsf(Lr[q].y - LJ.y)           \
                        + fabsf(Lr[q].z - LJ.z) + fabsf(Lr[q].w - LJ.w);          \
                int bk = (int)(d * BSCALE); if (bk > NBK - 1) bk = NBK - 1;       \
                if (jc_ != i0 + rq) {                                             \
                    atomicAdd(&hsum[rq * NBK + bk], __expf(logit));               \
                    atomicAdd(&hcnt[(rq >> 1) * NBK + bk], 1u << ((rq & 1) * 16));\
                    SL += logit;                                                  \
                }                                                                 \
            }                                                                     \
        }

    // ---- single pass over all 4096 columns: 8 waves x 16 cols = 128 cols/ct,
    //      32 ct-rounds, 2-deep register double-buffer ----
    float SL = 0.f;
    s16x8  bA[8], bB[8];
    float4 LjA, LjB;
    LOADB(bA, LjA, 0)
    for (int ct = 0; ct < 32; ct += 2) {
        LOADB(bB, LjB, ct + 1)               // prefetch next while computing cur
        COMPUTE(bA, LjA, ct)
        if (ct + 2 < 32) LOADB(bA, LjA, ct + 2)
        COMPUTE(bB, LjB, ct + 1)
    }
    __syncthreads();                         // B1: histograms complete

    // ---- wave w owns rows 2w, 2w+1: register suffix-CDF + count-weighted logs ----
    float term = 0.f;
    #pragma unroll
    for (int rr = 0; rr < 2; ++rr) {
        int row = w * 2 + rr;
        const float*    hs = hsum + row * NBK + L * 8;
        const unsigned* hc = hcnt + (row >> 1) * NBK + L * 8;
        int sh = (row & 1) * 16;
        float v[8];
        float fs = 0.f;
        #pragma unroll
        for (int k = 0; k < 8; ++k) { v[k] = hs[k]; fs += v[k]; }
        float s = fs;
        #pragma unroll
        for (int off = 1; off < 64; off <<= 1) {   // inclusive lane-suffix
            float u = __shfl_down(s, off, 64);
            if (L + off < 64) s += u;
        }
        float run = s - fs;                  // strictly-above-lane bucket sum
        #pragma unroll
        for (int k = 7; k >= 0; --k) {
            run += v[k];                     // inclusive suffix = denom of bucket 8L+k
            unsigned c = (hc[k] >> sh) & 0xFFFFu;
            if (c) term += (float)c * __logf(run + EPS_F);
        }
    }

    // ---- block reduce of (SL - term) = sum of pos_log_probs ----
    float acc = SL - term;
    #pragma unroll
    for (int off = 32; off > 0; off >>= 1)
        acc += __shfl_down(acc, off, 64);
    if (L == 0) scr[w] = acc;
    __syncthreads();                         // B2
    if (tid == 0) {
        float s = 0.f;
        #pragma unroll
        for (int w2 = 0; w2 < 8; ++w2) s += scr[w2];
        partial[blockIdx.x] = s;
    }
    #undef LOADB
    #undef COMPUTE
}

// ---------------- Kernel C: final reduce (256 panel partials) ----------------
__global__ __launch_bounds__(256) void final_kernel(
    const float* __restrict__ partial, float* __restrict__ out)
{
    __shared__ float red[4];
    int tid = threadIdx.x;
    float s = 0.f;
    for (int i = tid; i < N_TOT / RPP; i += 256) s += partial[i];
    #pragma unroll
    for (int off = 32; off > 0; off >>= 1)
        s += __shfl_down(s, off, 64);
    if ((tid & 63) == 0) red[tid >> 6] = s;
    __syncthreads();
    if (tid == 0) {
        double tot = (double)red[0] + red[1] + red[2] + red[3];
        out[0] = (float)(-tot / ((double)N_TOT * (N_TOT - 1)));   // loss = -sum/(n(n-1))
    }
}

extern "C" void kernel_launch(void* const* d_in, const int* in_sizes, int n_in,
                              void* d_out, int out_size, void* d_ws, size_t ws_size,
                              hipStream_t stream)
{
    const float* z_i  = (const float*)d_in[0];
    const float* z_j  = (const float*)d_in[1];
    const float* ph_i = (const float*)d_in[2];
    const float* ph_j = (const float*)d_in[3];

    unsigned short* fb      = (unsigned short*)d_ws;                  // 2 MB bf16
    float*          partial = (float*)(fb + (size_t)N_TOT * D_DIM);   // 1 KB

    normalize_kernel<<<N_TOT, 64, 0, stream>>>(z_i, z_j, fb);
    panel_kernel<<<N_TOT / RPP, 512, 0, stream>>>(fb, ph_i, ph_j, partial);
    final_kernel<<<1, 256, 0, stream>>>(partial, (float*)d_out);
}